// Round 13
// baseline (3968.369 us; speedup 1.0000x reference)
//
#include <hip/hip_runtime.h>

#define NB 128      // batch
#define NT 8192     // time steps
#define NS 128      // states
#define NE 6        // alphabet

typedef __attribute__((ext_vector_type(4))) int int32x4;

// XOR swizzle for the f32 alpha vector: elem i -> i ^ (4*(i>>5)).
// Keeps float4 chunks contiguous/aligned (only bits 2..3 flipped), and makes
// the 4 h-groups' b128 reads (base 128B apart = same bank) hit distinct banks.
__device__ __forceinline__ int swf(int i) { return i ^ (((i) >> 5) << 2); }

// ---------------------------------------------------------------------------
// Pure-fp32 VALU forward kernel: ONE chain per block, 128 blocks (128 CUs).
// Thread (s = tid>>2, h = tid&3): owns A[32h..32h+31][s] in 32 VGPRs.
// Per step: 8 swizzled b128 alpha reads + 32 FMA + 2 shfl + uniform-symbol
// emission select + 1 write + 1 barrier.  No MFMA, no precompute, no Ct.
// ---------------------------------------------------------------------------
__global__ void __launch_bounds__(512, 2)
hmm_valu_kernel(const int* __restrict__ obs, const float* __restrict__ I,
                const float* __restrict__ A, const float* __restrict__ Bm,
                float* __restrict__ out)
{
    __shared__ __align__(16) float alds[2][NS];  // dbuf alpha, f32, swizzled
    __shared__ int   obs_lds[128];               // 128-step obs chunk
    __shared__ float part[8];                    // per-wave Z partials

    const int tid = threadIdx.x;
    const int s   = tid >> 2;     // state column
    const int h   = tid & 3;      // k-quarter: k in [32h, 32h+32)
    const int w   = tid >> 6;     // wave
    const int b   = blockIdx.x;
    const int* orow = obs + (size_t)b * NT;

    // A-column quarter in registers (one-time, L2/L3-cached across blocks)
    float acol[32];
#pragma unroll
    for (int k = 0; k < 32; ++k) acol[k] = A[(32 * h + k) * NS + s];

    // emissions for this thread's state
    float er[NE];
#pragma unroll
    for (int o = 0; o < NE; ++o) er[o] = Bm[s * NE + o];

    // stage obs chunk 0
    if (tid < 32)
        *(int32x4*)&obs_lds[tid * 4] = *(const int32x4*)(orow + tid * 4);
    __syncthreads();

    // t = 0: alpha = I * em_0 (unnormalized)
    {
        const int o0 = obs_lds[0];
        float e = er[0];
        e = (o0 == 1) ? er[1] : e;
        e = (o0 == 2) ? er[2] : e;
        e = (o0 == 3) ? er[3] : e;
        e = (o0 == 4) ? er[4] : e;
        e = (o0 == 5) ? er[5] : e;
        if (h == 0) alds[0][swf(s)] = I[s] * e;
    }
    __syncthreads();

    float ll  = 0.f;
    int   cur = 0;

    for (int c = 0; c < 64; ++c) {
        if (c) {   // stage next obs chunk (alpha is double-buffered; safe)
            if (tid < 32)
                *(int32x4*)&obs_lds[tid * 4] =
                    *(const int32x4*)(orow + 128 * c + tid * 4);
            __syncthreads();
        }
        const int p0 = (c == 0) ? 1 : 0;
        for (int p = p0; p < 128; ++p) {
            const int t = 128 * c + p;
            const int o = obs_lds[p];    // block-uniform symbol -> broadcast

            // partial dot over k in [32h, 32h+32): 8 swizzled b128 reads
            float a0 = 0.f, a1 = 0.f, a2 = 0.f, a3 = 0.f;
#pragma unroll
            for (int q = 0; q < 8; ++q) {
                const float4 v4 =
                    *(const float4*)&alds[cur][(32 * h + 4 * q) ^ (4 * h)];
                a0 = fmaf(v4.x, acol[4 * q + 0], a0);
                a1 = fmaf(v4.y, acol[4 * q + 1], a1);
                a2 = fmaf(v4.z, acol[4 * q + 2], a2);
                a3 = fmaf(v4.w, acol[4 * q + 3], a3);
            }
            float d = (a0 + a1) + (a2 + a3);
            d += __shfl_xor(d, 1);       // sum over the 4 k-quarters
            d += __shfl_xor(d, 2);       // (all 4 lanes of a group get it)

            float e = er[0];
            e = (o == 1) ? er[1] : e;
            e = (o == 2) ? er[2] : e;
            e = (o == 3) ? er[3] : e;
            e = (o == 4) ? er[4] : e;
            e = (o == 5) ? er[5] : e;
            float v = d * e;

            const bool resc = ((t & 7) == 0) || (t == NT - 1);
            if (resc) {                  // block-uniform branch
                float z = v;
#pragma unroll
                for (int off = 4; off < 64; off <<= 1) z += __shfl_xor(z, off);
                if ((tid & 63) == 0) part[w] = z;   // z = 4 * wave state-sum
                __syncthreads();
                const float Z = 0.25f * (((part[0] + part[1]) + (part[2] + part[3]))
                                       + ((part[4] + part[5]) + (part[6] + part[7])));
                ll += logf(Z);
                v *= (1.0f / Z);
            }

            if (h == 0) alds[cur ^ 1][swf(s)] = v;
            __syncthreads();
            cur ^= 1;
        }
    }

    // ll telescopes to the full log-likelihood (final step was a rescale step)
    if (tid == 0) out[b] = ll;
}

extern "C" void kernel_launch(void* const* d_in, const int* in_sizes, int n_in,
                              void* d_out, int out_size, void* d_ws, size_t ws_size,
                              hipStream_t stream) {
    (void)in_sizes; (void)n_in; (void)d_ws; (void)ws_size; (void)out_size;
    const int*   obs = (const int*)d_in[0];
    const float* I   = (const float*)d_in[1];
    const float* A   = (const float*)d_in[2];
    const float* Bm  = (const float*)d_in[3];
    float*       out = (float*)d_out;

    hipLaunchKernelGGL(hmm_valu_kernel, dim3(NB), dim3(512), 0, stream,
                       obs, I, A, Bm, out);
}